// Round 10
// baseline (637.938 us; speedup 1.0000x reference)
//
#include <hip/hip_runtime.h>
#include <hip/hip_bf16.h>

// ---------------------------------------------------------------------------
// ProjectedConjugatedCSPNet: LN -> edge MLP (gather+sinemb+2xGEMM+silu) ->
// scatter-mean -> node MLP (2xGEMM+silu) -> residual add.
// R20: occupancy attack on edge_mlp. R15/R19 locked at 16 waves/CU by
// acc[4][4] = 64 AGPR + 64 VGPR = 128 regs (4 waves/SIMD); all scheduling
// tricks (interleave/nt/setprio) regressed because no runnable wave exists
// during stalls. Fix: 32-edge tiles -> acc[2][4] (32 AGPR) + smaller working
// set, __launch_bounds__(512,6) caps at 85 regs -> 6 waves/SIMD = 3 blocks/CU
// (+50% occupancy). LDS 33.8KB/block (3 fit). Staging remap: 16 thr/row,
// 6 items stride-64, recurrence step 32x (d-transitions wave-uniform).
// Costs (2x B-rereads via L2, 2x block overhead+boundary atomics) are
// second-order vs +50% latency hiding on a ~90%-stalled kernel.
// Others unchanged from R19 (fused prep, inlined aggdiv).
// ---------------------------------------------------------------------------

#include <type_traits>

typedef __attribute__((ext_vector_type(8))) short bfrag;   // 8 bf16 = 4 VGPRs
typedef __attribute__((ext_vector_type(4))) float ffrag;   // 4 fp32 acc

#define DEVI __device__ __forceinline__

constexpr int N_NODES = 10000;
constexpr int N_EDGES = 200000;
constexpr int HD      = 512;       // hidden dim
constexpr int NT      = HD / 16;   // 32 n-tiles of 16 cols
constexpr int SLABW   = 520;       // slab row stride in ushorts (1040 B)
constexpr int FSW     = 260;       // fs row stride in floats (32*260*4=33280)
constexpr int KSTR    = NT * 64 * 8;  // B ktile stride in ushorts (16384)
constexpr int EB      = 32;        // edges per block (was 64)

// silu without IEEE division: rcp is ~1 ulp fp32, far below the bf16
// quantization already applied to these values.
DEVI float silu_f(float v) {
    return v * __builtin_amdgcn_rcpf(1.0f + __expf(-v));
}

DEVI ushort f2bf(float f) {
    unsigned u = __float_as_uint(f);
    unsigned r = (u + 0x7fffu + ((u >> 16) & 1u)) >> 16;
    return (ushort)r;
}
DEVI float bf2f(ushort v) { return __uint_as_float((unsigned)v << 16); }

// permuted C-fragment column index: col (w*64+16n+ml) stored at (w*64+ml*4+n)
DEVI int cperm(int col) {
    return (col & ~63) | ((col & 15) << 2) | ((col >> 4) & 3);
}

// ------- Weight swizzle (device fn): W[K x 512] fp32 -> B-frag bf16 ---------
// mode 0: identity rows.
// mode 1: K-rows in cperm space (src = invperm(krow)).
// mode 2: identity for krow<512, invperm for krow>=512 (node GEMM1 [h;aggb]).
// mode 3: sin/cos interleaved K=768.
DEVI void wswz_f(int fid, const float* __restrict__ W, ushort* __restrict__ dst,
                 int mode) {
    int l  = fid & 63;
    int nn = (fid >> 6) & 31;
    int kk = fid >> 11;
    int col = nn * 16 + (l & 15);
    int kb  = kk * 32 + (l >> 4) * 8;
    union { ushort u16[8]; uint4 u4; } v;
    for (int j = 0; j < 8; ++j) {
        int krow = kb + j;
        int src;
        if (mode == 3) {
            int d = krow >> 8, rm = krow & 255, k = rm >> 1;
            src = ((rm & 1) ? 1414 : 1030) + d * 128 + k;
        } else if (mode == 1) {
            src = (krow & ~63) | ((krow & 3) << 4) | ((krow >> 2) & 15);
        } else if (mode == 2) {
            src = (krow < 512) ? krow
                : ((krow & ~63) | ((krow & 3) << 4) | ((krow >> 2) & 15));
        } else {
            src = krow;
        }
        v.u16[j] = f2bf(W[(size_t)src * HD + col]);
    }
    *(uint4*)(dst + (size_t)fid * 8) = v.u4;
}

// ---------------- fused prep: zero + 6x wswz + latb -------------------------
__global__ void prep_kernel(const float* __restrict__ W_e1, const float* __restrict__ W_e2,
                            const float* __restrict__ W_n1, const float* __restrict__ W_n2,
                            const float* __restrict__ latt, const float* __restrict__ b_e1,
                            ushort* __restrict__ w1a, ushort* __restrict__ w1b,
                            ushort* __restrict__ w1c, ushort* __restrict__ w2s,
                            ushort* __restrict__ wn1, ushort* __restrict__ wn2,
                            float* __restrict__ LATBp,
                            int* __restrict__ c32, float4* __restrict__ agg4) {
    int b = blockIdx.x, t = threadIdx.x;
    if (b < 5000) {
        int i = b * 256 + t;                 // exactly N_NODES*HD/4 threads
        if (i < N_NODES) c32[i] = 0;
        agg4[i] = float4{0.f, 0.f, 0.f, 0.f};
        return;
    }
    b -= 5000;
    if (b < 128) { wswz_f(b * 256 + t, W_e1, w1a, 0); return; }
    b -= 128;
    if (b < 128) { wswz_f(b * 256 + t, W_e1 + (size_t)HD * HD, w1b, 0); return; }
    b -= 128;
    if (b < 192) { wswz_f(b * 256 + t, W_e1, w1c, 3); return; }
    b -= 192;
    if (b < 128) { wswz_f(b * 256 + t, W_e2, w2s, 1); return; }
    b -= 128;
    if (b < 256) { wswz_f(b * 256 + t, W_n1, wn1, 2); return; }
    b -= 256;
    if (b < 128) { wswz_f(b * 256 + t, W_n2, wn2, 1); return; }
    b -= 128;
    // latb: b in [0,50), 2 cols per thread
    for (int cc = t; cc < HD; cc += 256) {
        float a = b_e1[cc];
        for (int c = 0; c < 6; ++c)
            a += latt[b * 6 + c] * W_e1[(size_t)(1024 + c) * HD + cc];
        LATBp[(size_t)b * HD + cperm(cc)] = a;
    }
}

// ---------------- LayerNorm: node_features -> h (bf16) ----------------------
__global__ void ln_kernel(const float* __restrict__ x, const float* __restrict__ g,
                          const float* __restrict__ b, ushort* __restrict__ h) {
    __shared__ float wred[8];
    __shared__ float mb[2];
    int row = blockIdx.x;
    int t = threadIdx.x;              // 256 threads
    const float* xr = x + (size_t)row * HD;
    float2 xv = *(const float2*)(xr + 2 * t);
    float s = xv.x + xv.y, qq = xv.x * xv.x + xv.y * xv.y;
    for (int o = 32; o; o >>= 1) { s += __shfl_down(s, o); qq += __shfl_down(qq, o); }
    int w = t >> 6, l = t & 63;
    if (l == 0) { wred[w] = s; wred[w + 4] = qq; }
    __syncthreads();
    if (t == 0) {
        float S = wred[0] + wred[1] + wred[2] + wred[3];
        float Q = wred[4] + wred[5] + wred[6] + wred[7];
        float m = S * (1.0f / HD);
        float v = Q * (1.0f / HD) - m * m;
        mb[0] = m; mb[1] = rsqrtf(v + 1e-5f);
    }
    __syncthreads();
    float m = mb[0], rs = mb[1];
    float2 gv = *(const float2*)(g + 2 * t);
    float2 bv = *(const float2*)(b + 2 * t);
    __hip_bfloat162 o2 = __float22bfloat162_rn(
        float2{(xv.x - m) * rs * gv.x + bv.x, (xv.y - m) * rs * gv.y + bv.y});
    *(__hip_bfloat162*)(h + (size_t)row * HD + 2 * t) = o2;
}

// ---------------- CSR build -------------------------------------------------
__global__ void hist_kernel(const int* __restrict__ eidx, int* __restrict__ cnt32) {
    int e = blockIdx.x * 256 + threadIdx.x;
    if (e < N_EDGES) atomicAdd(&cnt32[eidx[e]], 1);
}

__global__ void scan_kernel(const int* __restrict__ cnt32, int* __restrict__ row_ptr,
                            int* __restrict__ cursor) {
    __shared__ int buf[1024];
    int t = threadIdx.x;              // 1024 threads
    int base = t * 10;
    int loc[10]; int s = 0;
    for (int i = 0; i < 10; ++i) {
        int idx = base + i;
        int v = (idx < N_NODES) ? cnt32[idx] : 0;
        loc[i] = s; s += v;
    }
    buf[t] = s; __syncthreads();
    for (int off = 1; off < 1024; off <<= 1) {
        int v = 0; if (t >= off) v = buf[t - off];
        __syncthreads();
        buf[t] += v; __syncthreads();
    }
    int excl = buf[t] - s;
    for (int i = 0; i < 10; ++i) {
        int idx = base + i;
        if (idx < N_NODES) { int p = excl + loc[i]; row_ptr[idx] = p; cursor[idx] = p; }
    }
    if (t == 0) row_ptr[N_NODES] = N_EDGES;
}

__global__ void csr_fill(const int* __restrict__ eidx, int* __restrict__ cursor,
                         int* __restrict__ ebuf) {
    int e = blockIdx.x * 256 + threadIdx.x;
    if (e >= N_EDGES) return;
    int pos = atomicAdd(&cursor[eidx[e]], 1);
    ebuf[pos] = e;
}

__global__ void sentinel_kernel(float* o, int n) {
    int i = blockIdx.x * 256 + threadIdx.x;
    if (i < n) o[i] = 123456789.0f;
}

// ---------------- rotated-prefetch kloop ------------------------------------
template <int KTN, int MT>
DEVI void kloop_rot(ffrag (&acc)[MT][4], const ushort* sl, const ushort* bp0,
                    int ml, int q) {
    bfrag b_[4];
    const ushort* bp = bp0;
    #pragma unroll
    for (int n = 0; n < 4; ++n) b_[n] = *(const bfrag*)(bp + n * 512);
    #pragma unroll
    for (int p = 0; p < KTN; ++p) {
        bfrag a_[MT];
        #pragma unroll
        for (int m = 0; m < MT; ++m)
            a_[m] = *(const bfrag*)&sl[(16 * m + ml) * SLABW + p * 32 + q * 8];
        const ushort* bpn = bp + KSTR;
        #pragma unroll
        for (int n = 0; n < 4; ++n) {
            #pragma unroll
            for (int m = 0; m < MT; ++m)
                acc[m][n] = __builtin_amdgcn_mfma_f32_16x16x32_bf16(a_[m], b_[n], acc[m][n], 0, 0, 0);
            if (p + 1 < KTN) b_[n] = *(const bfrag*)(bpn + n * 512);
        }
        bp = bpn;
    }
}

// ---------------- HA/HB producer (32 nodes x 512 per block, grid.y=A/B) -----
__global__ __launch_bounds__(512, 4) void hab_gemm(
    const ushort* __restrict__ h, const ushort* __restrict__ w1a_s,
    const ushort* __restrict__ w1b_s, ushort* __restrict__ HAp,
    ushort* __restrict__ HBp) {

    __shared__ __align__(16) ushort slab[32 * SLABW];   // 33 KB
    const int t = threadIdx.x;
    const int w = t >> 6;
    const int l = t & 63;
    const int q = l >> 4;
    const int ml = l & 15;
    const int rowbase = blockIdx.x * 32;
    const ushort* Bswz = blockIdx.y ? w1b_s : w1a_s;
    ushort* out = blockIdx.y ? HBp : HAp;

    for (int j = 0; j < 4; ++j) {
        int rr = w * 4 + j;
        int row = rowbase + rr;
        if (row >= N_NODES) row = N_NODES - 1;
        *(uint4*)&slab[rr * SLABW + l * 8] =
            *(const uint4*)(h + (size_t)row * HD + l * 8);
    }
    __syncthreads();

    ffrag acc[2][4];
    for (int m = 0; m < 2; ++m)
        for (int n = 0; n < 4; ++n)
            acc[m][n] = (ffrag){0.f, 0.f, 0.f, 0.f};

    kloop_rot<16, 2>(acc, slab, Bswz + ((size_t)(w << 2) * 64 + l) * 8, ml, q);

    for (int m = 0; m < 2; ++m)
        for (int rr = 0; rr < 4; ++rr) {
            int grow = rowbase + 16 * m + 4 * q + rr;
            if (grow < N_NODES) {
                union { __hip_bfloat162 h2[2]; ushort4 u4; } pk;
                pk.h2[0] = __float22bfloat162_rn(float2{acc[m][0][rr], acc[m][1][rr]});
                pk.h2[1] = __float22bfloat162_rn(float2{acc[m][2][rr], acc[m][3][rr]});
                *(ushort4*)(out + (size_t)grow * HD + w * 64 + ml * 4) = pk.u4;
            }
        }
}

// ---------------- Fused edge MLP (32 edges x 512 cols per block) ------------
// acc[2][4] (32 AGPR) + launch_bounds(512,6) -> 6 waves/SIMD, 3 blocks/CU.
// Staging: 16 threads/row, 6 items of stride-64 cols, recurrence step 32x.
__global__ __launch_bounds__(512, 6) void edge_mlp(
    const ushort* __restrict__ HAp,   const ushort* __restrict__ HBp,
    const float* __restrict__ LATBp,  const ushort* __restrict__ w1c,
    const ushort* __restrict__ w2s,   const float* __restrict__ b2,
    float* __restrict__ agg,
    const int* __restrict__ edge_index, const int* __restrict__ e2g,
    const float* __restrict__ frac_diff, const int* __restrict__ ebuf) {

    __shared__ __align__(16) ushort slab[EB * SLABW];     // 33280 B
    __shared__ int   ssrc[EB];
    __shared__ int   sdst[EB];
    __shared__ int   sgrp[EB];
    __shared__ float sfd[EB * 3];

    const int t = threadIdx.x;        // 512 threads = 8 waves
    const int w = t >> 6;
    const int l = t & 63;
    const int q = l >> 4;
    const int ml = l & 15;
    const int rowbase = blockIdx.x * EB;

    if (t < EB) {
        int eid = ebuf[rowbase + t];
        ssrc[t] = edge_index[eid];
        sdst[t] = edge_index[N_EDGES + eid];
        sgrp[t] = e2g[eid];
        for (int c = 0; c < 3; ++c) sfd[t * 3 + c] = frac_diff[(size_t)eid * 3 + c];
    }
    __syncthreads();

    // ---- acc init: direct permuted loads (L2/L3-hot) ----
    ffrag acc[2][4];
    {
        const int cb = w * 64 + ml * 4;
        for (int m = 0; m < 2; ++m)
            for (int rr = 0; rr < 4; ++rr) {
                int rowl = 16 * m + 4 * q + rr;
                ushort4 a4 = *(const ushort4*)(HAp + (size_t)ssrc[rowl] * HD + cb);
                ushort4 h4 = *(const ushort4*)(HBp + (size_t)sdst[rowl] * HD + cb);
                float4  l4 = *(const float4*)(LATBp + (size_t)sgrp[rowl] * HD + cb);
                acc[m][0][rr] = bf2f(a4.x) + bf2f(h4.x) + l4.x;
                acc[m][1][rr] = bf2f(a4.y) + bf2f(h4.y) + l4.y;
                acc[m][2][rr] = bf2f(a4.z) + bf2f(h4.z) + l4.z;
                acc[m][3][rr] = bf2f(a4.w) + bf2f(h4.w) + l4.w;
            }
    }

    const int r  = t >> 4;            // staging row 0..31 (16 threads/row)
    const int c0 = (t & 15) * 4;      // staging col 0..60 step 4

    // ---- sin/cos staging: 6 items of stride-64 cols, recurrence step 32x --
    auto stage = [&](int phase) {
        float s = 0.f, c = 0.f, sx = 0.f, cx = 0.f, s32 = 0.f, c32 = 0.f;
        int dcur = -1;
        #pragma unroll
        for (int i = 0; i < 6; ++i) {
            int cc = c0 + 64 * i;                // 0..380 slab col
            int cp = phase * 384 + cc;           // global C-col
            int d = cp >> 8;
            if (d != dcur) {                     // wave-uniform transition
                dcur = d;
                float x = sfd[r * 3 + d];
                float rx = __builtin_amdgcn_fractf(x);
                sx  = __builtin_amdgcn_sinf(rx);
                cx  = __builtin_amdgcn_cosf(rx);
                float r32 = __builtin_amdgcn_fractf(32.0f * x);
                s32 = __builtin_amdgcn_sinf(r32);
                c32 = __builtin_amdgcn_cosf(r32);
                int k0 = (cp & 255) >> 1;
                float r0 = __builtin_amdgcn_fractf((float)k0 * x);
                s = __builtin_amdgcn_sinf(r0);
                c = __builtin_amdgcn_cosf(r0);
            } else {
                float ns = s * c32 + c * s32;    // advance by 32x
                float nc = c * c32 - s * s32;
                s = ns; c = nc;
            }
            float s1 = s * cx + c * sx;          // partner k+1 (step x)
            float c1 = c * cx - s * sx;
            union { __hip_bfloat162 h2[2]; ushort4 u4; } pk;
            pk.h2[0] = __float22bfloat162_rn(float2{s, c});
            pk.h2[1] = __float22bfloat162_rn(float2{s1, c1});
            *(ushort4*)&slab[r * SLABW + cc] = pk.u4;
        }
    };

    const ushort* bpw1 = w1c + ((size_t)(w << 2) * 64 + l) * 8;
    const ushort* bpw2 = w2s + ((size_t)(w << 2) * 64 + l) * 8;

    stage(0);
    __syncthreads();
    kloop_rot<12, 2>(acc, slab, bpw1, ml, q);
    __syncthreads();
    stage(1);
    __syncthreads();
    kloop_rot<12, 2>(acc, slab, bpw1 + (size_t)12 * KSTR, ml, q);
    __syncthreads();

    // ---- e1 = silu(acc) -> slab in cperm layout (cvt_pk + b64); reset acc --
    for (int m = 0; m < 2; ++m)
        for (int rr = 0; rr < 4; ++rr) {
            int rowl = 16 * m + 4 * q + rr;
            union { __hip_bfloat162 h2[2]; ushort4 u4; } pk;
            pk.h2[0] = __float22bfloat162_rn(
                float2{silu_f(acc[m][0][rr]), silu_f(acc[m][1][rr])});
            pk.h2[1] = __float22bfloat162_rn(
                float2{silu_f(acc[m][2][rr]), silu_f(acc[m][3][rr])});
            *(ushort4*)&slab[rowl * SLABW + w * 64 + ml * 4] = pk.u4;
        }
    for (int m = 0; m < 2; ++m)
        for (int n = 0; n < 4; ++n)
            acc[m][n] = (ffrag){0.f, 0.f, 0.f, 0.f};
    __syncthreads();

    // ---- GEMM2 straight from the perm slab (w2s has invperm K-rows) ----
    kloop_rot<16, 2>(acc, slab, bpw2, ml, q);

    // ---- silu + b2 -> cperm fp32 fs (float4) + split segment reduce ----
    float* fs = (float*)slab;            // 32 x FSW fp32 (33280 B exact)
    float bv0 = b2[w * 64 + 0 * 16 + ml];
    float bv1 = b2[w * 64 + 1 * 16 + ml];
    float bv2 = b2[w * 64 + 2 * 16 + ml];
    float bv3 = b2[w * 64 + 3 * 16 + ml];
    for (int hh = 0; hh < 2; ++hh) {
        __syncthreads();
        if ((w >> 2) == hh) {
            int lcb = w * 64 + ml * 4 - hh * 256;   // local cperm col base
            for (int m = 0; m < 2; ++m)
                for (int rr = 0; rr < 4; ++rr) {
                    int rowl = 16 * m + 4 * q + rr;
                    float4 v = float4{silu_f(acc[m][0][rr] + bv0),
                                      silu_f(acc[m][1][rr] + bv1),
                                      silu_f(acc[m][2][rr] + bv2),
                                      silu_f(acc[m][3][rr] + bv3)};
                    *(float4*)&fs[rowl * FSW + lcb] = v;
                }
        }
        __syncthreads();
        {
            int col = t & 255;
            int r0 = (t >> 8) * 16;          // 2 halves of 16 rows
            int cur = ssrc[r0];
            float run = 0.f;
            for (int j = 0; j < 16; ++j) {
                int rr2 = r0 + j;
                int nd = ssrc[rr2];
                if (nd != cur) {
                    unsafeAtomicAdd(&agg[(size_t)cur * HD + hh * 256 + col], run);
                    run = 0.f; cur = nd;
                }
                run += fs[rr2 * FSW + col];
            }
            unsafeAtomicAdd(&agg[(size_t)cur * HD + hh * 256 + col], run);
        }
    }
}

// ---------------- Fused node MLP (32 nodes x 512 cols per block) ------------
// aggdiv inlined: second staging reads agg fp32 + rp, divides by deg
// (wave-uniform per row), converts to bf16 in-register.
__global__ __launch_bounds__(512, 4) void node_mlp(
    const ushort* __restrict__ h,     const float* __restrict__ agg,
    const int* __restrict__ rp,
    const ushort* __restrict__ wn1s,  const ushort* __restrict__ wn2s,
    const float* __restrict__ b1,     const float* __restrict__ b2,
    const float* __restrict__ nf,     float* __restrict__ out) {

    __shared__ __align__(16) ushort slab[32 * SLABW];   // 33 KB

    const int t = threadIdx.x;        // 512 threads = 8 waves
    const int w = t >> 6;
    const int l = t & 63;
    const int q = l >> 4;
    const int ml = l & 15;
    const int rowbase = blockIdx.x * 32;

    ffrag acc[2][4];
    for (int m = 0; m < 2; ++m)
        for (int n = 0; n < 4; ++n)
            acc[m][n] = (ffrag){0.f, 0.f, 0.f, 0.f};

    const ushort* bp1 = wn1s + ((size_t)(w << 2) * 64 + l) * 8;
    const ushort* bp2 = wn2s + ((size_t)(w << 2) * 64 + l) * 8;

    // stage h rows
    for (int j = 0; j < 4; ++j) {
        int rr = w * 4 + j;
        int row = rowbase + rr;
        if (row >= N_NODES) row = N_NODES - 1;
        *(uint4*)&slab[rr * SLABW + l * 8] =
            *(const uint4*)(h + (size_t)row * HD + l * 8);
    }
    __syncthreads();
    kloop_rot<16, 2>(acc, slab, bp1, ml, q);
    __syncthreads();

    // stage agg rows / deg -> bf16 (inlined aggdiv)
    for (int j = 0; j < 4; ++j) {
        int rr = w * 4 + j;
        int row = rowbase + rr;
        if (row >= N_NODES) row = N_NODES - 1;
        int deg = rp[row + 1] - rp[row];
        float rc = __builtin_amdgcn_rcpf((float)max(deg, 1));
        const float4* ap = (const float4*)(agg + (size_t)row * HD + l * 8);
        float4 v0 = ap[0], v1 = ap[1];
        union { __hip_bfloat162 h2[4]; uint4 u4; } pk;
        pk.h2[0] = __float22bfloat162_rn(float2{v0.x * rc, v0.y * rc});
        pk.h2[1] = __float22bfloat162_rn(float2{v0.z * rc, v0.w * rc});
        pk.h2[2] = __float22bfloat162_rn(float2{v1.x * rc, v1.y * rc});
        pk.h2[3] = __float22bfloat162_rn(float2{v1.z * rc, v1.w * rc});
        *(uint4*)&slab[rr * SLABW + l * 8] = pk.u4;
    }
    __syncthreads();
    kloop_rot<16, 2>(acc, slab, bp1 + (size_t)16 * KSTR, ml, q);
    __syncthreads();

    {
        float bv[4];
        for (int n = 0; n < 4; ++n) bv[n] = b1[w * 64 + n * 16 + ml];
        for (int m = 0; m < 2; ++m)
            for (int rr = 0; rr < 4; ++rr) {
                int rowl = 16 * m + 4 * q + rr;
                union { __hip_bfloat162 h2[2]; ushort4 u4; } pk;
                pk.h2[0] = __float22bfloat162_rn(
                    float2{silu_f(acc[m][0][rr] + bv[0]), silu_f(acc[m][1][rr] + bv[1])});
                pk.h2[1] = __float22bfloat162_rn(
                    float2{silu_f(acc[m][2][rr] + bv[2]), silu_f(acc[m][3][rr] + bv[3])});
                *(ushort4*)&slab[rowl * SLABW + w * 64 + ml * 4] = pk.u4;
            }
    }
    for (int m = 0; m < 2; ++m)
        for (int n = 0; n < 4; ++n)
            acc[m][n] = (ffrag){0.f, 0.f, 0.f, 0.f};
    __syncthreads();

    kloop_rot<16, 2>(acc, slab, bp2, ml, q);

    for (int n = 0; n < 4; ++n) {
        int cg = w * 64 + n * 16 + ml;
        float bv = b2[cg];
        for (int m = 0; m < 2; ++m)
            for (int rr = 0; rr < 4; ++rr) {
                int rowl = 16 * m + 4 * q + rr;
                int row = rowbase + rowl;
                if (row < N_NODES) {
                    float v = silu_f(acc[m][n][rr] + bv);
                    out[(size_t)row * HD + cg] = nf[(size_t)row * HD + cg] + v;
                }
            }
    }
}

// ---------------------------------------------------------------------------
extern "C" void kernel_launch(void* const* d_in, const int* in_sizes, int n_in,
                              void* d_out, int out_size, void* d_ws, size_t ws_size,
                              hipStream_t stream) {
    const float* nf      = (const float*)d_in[0];
    const float* latt    = (const float*)d_in[1];
    const int*   eidx    = (const int*)d_in[2];
    const int*   e2g     = (const int*)d_in[3];
    const float* fd      = (const float*)d_in[4];
    const float* ln_g    = (const float*)d_in[6];
    const float* ln_b    = (const float*)d_in[7];
    const float* W_e1    = (const float*)d_in[8];
    const float* b_e1    = (const float*)d_in[9];
    const float* W_e2    = (const float*)d_in[10];
    const float* b_e2    = (const float*)d_in[11];
    const float* W_n1    = (const float*)d_in[12];
    const float* b_n1    = (const float*)d_in[13];
    const float* W_n2    = (const float*)d_in[14];
    const float* b_n2    = (const float*)d_in[15];
    float* out = (float*)d_out;

    auto al = [](size_t x) { return (x + 511) & ~(size_t)511; };
    size_t off_h    = 0;                         size_t sz_h    = (size_t)N_NODES * HD * 2;
    size_t off_w1a  = al(off_h + sz_h);          size_t sz_w1a  = (size_t)HD * HD * 2;
    size_t off_w1b  = al(off_w1a + sz_w1a);      size_t sz_w1b  = (size_t)HD * HD * 2;
    size_t off_w1c  = al(off_w1b + sz_w1b);      size_t sz_w1c  = (size_t)768 * HD * 2;
    size_t off_w2   = al(off_w1c + sz_w1c);      size_t sz_w2   = (size_t)HD * HD * 2;
    size_t off_wn1  = al(off_w2 + sz_w2);        size_t sz_wn1  = (size_t)2 * HD * HD * 2;
    size_t off_wn2  = al(off_wn1 + sz_wn1);      size_t sz_wn2  = (size_t)HD * HD * 2;
    size_t off_ha   = al(off_wn2 + sz_wn2);      size_t sz_ha   = (size_t)N_NODES * HD * 2;
    size_t off_hb   = al(off_ha + sz_ha);        size_t sz_hb   = (size_t)N_NODES * HD * 2;
    size_t off_lb   = al(off_hb + sz_hb);        size_t sz_lb   = (size_t)50 * HD * 4;
    size_t off_c32  = al(off_lb + sz_lb);        size_t sz_c32  = (size_t)N_NODES * 4;
    size_t off_cur  = al(off_c32 + sz_c32);      size_t sz_cur  = (size_t)N_NODES * 4;
    size_t off_rp   = al(off_cur + sz_cur);      size_t sz_rp   = (size_t)(N_NODES + 1) * 4;
    size_t off_ebuf = al(off_rp + sz_rp);        size_t sz_ebuf = (size_t)N_EDGES * 4;
    size_t off_agg  = al(off_ebuf + sz_ebuf);    size_t sz_agg  = (size_t)N_NODES * HD * 4;
    size_t need     = off_agg + sz_agg;

    if (ws_size < need) {
        sentinel_kernel<<<(out_size + 255) / 256, 256, 0, stream>>>(out, out_size);
        return;
    }

    char* ws = (char*)d_ws;
    ushort* h     = (ushort*)(ws + off_h);
    ushort* w1a_s = (ushort*)(ws + off_w1a);
    ushort* w1b_s = (ushort*)(ws + off_w1b);
    ushort* w1c_s = (ushort*)(ws + off_w1c);
    ushort* w2s   = (ushort*)(ws + off_w2);
    ushort* wn1s  = (ushort*)(ws + off_wn1);
    ushort* wn2s  = (ushort*)(ws + off_wn2);
    ushort* HAp   = (ushort*)(ws + off_ha);
    ushort* HBp   = (ushort*)(ws + off_hb);
    float*  LATBp = (float*)(ws + off_lb);
    int*    c32   = (int*)(ws + off_c32);
    int*    cur   = (int*)(ws + off_cur);
    int*    rp    = (int*)(ws + off_rp);
    int*    ebuf  = (int*)(ws + off_ebuf);
    float*  agg   = (float*)(ws + off_agg);

    // fused prep: zero + 6x wswz + latb (one launch, 6010 blocks)
    prep_kernel<<<6010, 256, 0, stream>>>(
        W_e1, W_e2, W_n1, W_n2, latt, b_e1,
        w1a_s, w1b_s, w1c_s, w2s, wn1s, wn2s, LATBp, c32, (float4*)agg);

    // CSR build (edges sorted by src node)
    hist_kernel<<<(N_EDGES + 255) / 256, 256, 0, stream>>>(eidx, c32);
    scan_kernel<<<1, 1024, 0, stream>>>(c32, rp, cur);
    csr_fill<<<(N_EDGES + 255) / 256, 256, 0, stream>>>(eidx, cur, ebuf);

    // LN then node-level hoist (HAp, HBp)
    ln_kernel<<<N_NODES, 256, 0, stream>>>(nf, ln_g, ln_b, h);
    hab_gemm<<<dim3(313, 2), 512, 0, stream>>>(h, w1a_s, w1b_s, HAp, HBp);

    // fused edge MLP (CSR order, 32 edges/block) -> agg (cperm col space)
    edge_mlp<<<N_EDGES / EB, 512, 0, stream>>>(
        HAp, HBp, LATBp, w1c_s, w2s, b_e2, agg, eidx, e2g, fd, ebuf);

    // fused node MLP (aggdiv inlined; 313 blocks)
    int nblocks = (N_NODES + 31) / 32;
    node_mlp<<<nblocks, 512, 0, stream>>>(h, agg, rp, wn1s, wn2s, b_n1, b_n2, nf, out);
}

// Round 11
// 501.307 us; speedup vs baseline: 1.2725x; 1.2725x over previous
//
#include <hip/hip_runtime.h>
#include <hip/hip_bf16.h>

// ---------------------------------------------------------------------------
// ProjectedConjugatedCSPNet: LN -> edge MLP (gather+sinemb+2xGEMM+silu) ->
// scatter-mean -> node MLP (2xGEMM+silu) -> residual add.
// R21: edge_mlp reverted to exact R19/R15 form (318us verified optimum; R20's
// M=32 tile flipped it L2-BW-bound: per-thread acc = M_tile pins M=64 as the
// traffic/occupancy balance point). New: ln_kernel fused into hab_gemm -
// wave-per-row butterfly LN during staging (8 vals/lane x 64 lanes), bf16
// pack to slab + h write (y==0 only). Kills a 10000-block latency-bound
// launch; HBM net-neutral. Others unchanged from R19.
// ---------------------------------------------------------------------------

#include <type_traits>

typedef __attribute__((ext_vector_type(8))) short bfrag;   // 8 bf16 = 4 VGPRs
typedef __attribute__((ext_vector_type(4))) float ffrag;   // 4 fp32 acc

#define DEVI __device__ __forceinline__

constexpr int N_NODES = 10000;
constexpr int N_EDGES = 200000;
constexpr int HD      = 512;       // hidden dim
constexpr int NT      = HD / 16;   // 32 n-tiles of 16 cols
constexpr int SLABW   = 520;       // slab row stride in ushorts (1040 B)
constexpr int FSW     = 260;       // fs row stride in floats (64*260*4=66560)
constexpr int KSTR    = NT * 64 * 8;  // B ktile stride in ushorts (16384)

// silu without IEEE division: rcp is ~1 ulp fp32, far below the bf16
// quantization already applied to these values.
DEVI float silu_f(float v) {
    return v * __builtin_amdgcn_rcpf(1.0f + __expf(-v));
}

DEVI ushort f2bf(float f) {
    unsigned u = __float_as_uint(f);
    unsigned r = (u + 0x7fffu + ((u >> 16) & 1u)) >> 16;
    return (ushort)r;
}
DEVI float bf2f(ushort v) { return __uint_as_float((unsigned)v << 16); }

// permuted C-fragment column index: col (w*64+16n+ml) stored at (w*64+ml*4+n)
DEVI int cperm(int col) {
    return (col & ~63) | ((col & 15) << 2) | ((col >> 4) & 3);
}

// ------- Weight swizzle (device fn): W[K x 512] fp32 -> B-frag bf16 ---------
// mode 0: identity rows.
// mode 1: K-rows in cperm space (src = invperm(krow)).
// mode 2: identity for krow<512, invperm for krow>=512 (node GEMM1 [h;aggb]).
// mode 3: sin/cos interleaved K=768.
DEVI void wswz_f(int fid, const float* __restrict__ W, ushort* __restrict__ dst,
                 int mode) {
    int l  = fid & 63;
    int nn = (fid >> 6) & 31;
    int kk = fid >> 11;
    int col = nn * 16 + (l & 15);
    int kb  = kk * 32 + (l >> 4) * 8;
    union { ushort u16[8]; uint4 u4; } v;
    for (int j = 0; j < 8; ++j) {
        int krow = kb + j;
        int src;
        if (mode == 3) {
            int d = krow >> 8, rm = krow & 255, k = rm >> 1;
            src = ((rm & 1) ? 1414 : 1030) + d * 128 + k;
        } else if (mode == 1) {
            src = (krow & ~63) | ((krow & 3) << 4) | ((krow >> 2) & 15);
        } else if (mode == 2) {
            src = (krow < 512) ? krow
                : ((krow & ~63) | ((krow & 3) << 4) | ((krow >> 2) & 15));
        } else {
            src = krow;
        }
        v.u16[j] = f2bf(W[(size_t)src * HD + col]);
    }
    *(uint4*)(dst + (size_t)fid * 8) = v.u4;
}

// ---------------- fused prep: zero + 6x wswz + latb -------------------------
__global__ void prep_kernel(const float* __restrict__ W_e1, const float* __restrict__ W_e2,
                            const float* __restrict__ W_n1, const float* __restrict__ W_n2,
                            const float* __restrict__ latt, const float* __restrict__ b_e1,
                            ushort* __restrict__ w1a, ushort* __restrict__ w1b,
                            ushort* __restrict__ w1c, ushort* __restrict__ w2s,
                            ushort* __restrict__ wn1, ushort* __restrict__ wn2,
                            float* __restrict__ LATBp,
                            int* __restrict__ c32, float4* __restrict__ agg4) {
    int b = blockIdx.x, t = threadIdx.x;
    if (b < 5000) {
        int i = b * 256 + t;                 // exactly N_NODES*HD/4 threads
        if (i < N_NODES) c32[i] = 0;
        agg4[i] = float4{0.f, 0.f, 0.f, 0.f};
        return;
    }
    b -= 5000;
    if (b < 128) { wswz_f(b * 256 + t, W_e1, w1a, 0); return; }
    b -= 128;
    if (b < 128) { wswz_f(b * 256 + t, W_e1 + (size_t)HD * HD, w1b, 0); return; }
    b -= 128;
    if (b < 192) { wswz_f(b * 256 + t, W_e1, w1c, 3); return; }
    b -= 192;
    if (b < 128) { wswz_f(b * 256 + t, W_e2, w2s, 1); return; }
    b -= 128;
    if (b < 256) { wswz_f(b * 256 + t, W_n1, wn1, 2); return; }
    b -= 256;
    if (b < 128) { wswz_f(b * 256 + t, W_n2, wn2, 1); return; }
    b -= 128;
    // latb: b in [0,50), 2 cols per thread
    for (int cc = t; cc < HD; cc += 256) {
        float a = b_e1[cc];
        for (int c = 0; c < 6; ++c)
            a += latt[b * 6 + c] * W_e1[(size_t)(1024 + c) * HD + cc];
        LATBp[(size_t)b * HD + cperm(cc)] = a;
    }
}

// ---------------- CSR build -------------------------------------------------
__global__ void hist_kernel(const int* __restrict__ eidx, int* __restrict__ cnt32) {
    int e = blockIdx.x * 256 + threadIdx.x;
    if (e < N_EDGES) atomicAdd(&cnt32[eidx[e]], 1);
}

__global__ void scan_kernel(const int* __restrict__ cnt32, int* __restrict__ row_ptr,
                            int* __restrict__ cursor) {
    __shared__ int buf[1024];
    int t = threadIdx.x;              // 1024 threads
    int base = t * 10;
    int loc[10]; int s = 0;
    for (int i = 0; i < 10; ++i) {
        int idx = base + i;
        int v = (idx < N_NODES) ? cnt32[idx] : 0;
        loc[i] = s; s += v;
    }
    buf[t] = s; __syncthreads();
    for (int off = 1; off < 1024; off <<= 1) {
        int v = 0; if (t >= off) v = buf[t - off];
        __syncthreads();
        buf[t] += v; __syncthreads();
    }
    int excl = buf[t] - s;
    for (int i = 0; i < 10; ++i) {
        int idx = base + i;
        if (idx < N_NODES) { int p = excl + loc[i]; row_ptr[idx] = p; cursor[idx] = p; }
    }
    if (t == 0) row_ptr[N_NODES] = N_EDGES;
}

__global__ void csr_fill(const int* __restrict__ eidx, int* __restrict__ cursor,
                         int* __restrict__ ebuf) {
    int e = blockIdx.x * 256 + threadIdx.x;
    if (e >= N_EDGES) return;
    int pos = atomicAdd(&cursor[eidx[e]], 1);
    ebuf[pos] = e;
}

__global__ void sentinel_kernel(float* o, int n) {
    int i = blockIdx.x * 256 + threadIdx.x;
    if (i < n) o[i] = 123456789.0f;
}

// ---------------- rotated-prefetch kloop ------------------------------------
template <int KTN, int MT>
DEVI void kloop_rot(ffrag (&acc)[MT][4], const ushort* sl, const ushort* bp0,
                    int ml, int q) {
    bfrag b_[4];
    const ushort* bp = bp0;
    #pragma unroll
    for (int n = 0; n < 4; ++n) b_[n] = *(const bfrag*)(bp + n * 512);
    #pragma unroll
    for (int p = 0; p < KTN; ++p) {
        bfrag a_[MT];
        #pragma unroll
        for (int m = 0; m < MT; ++m)
            a_[m] = *(const bfrag*)&sl[(16 * m + ml) * SLABW + p * 32 + q * 8];
        const ushort* bpn = bp + KSTR;
        #pragma unroll
        for (int n = 0; n < 4; ++n) {
            #pragma unroll
            for (int m = 0; m < MT; ++m)
                acc[m][n] = __builtin_amdgcn_mfma_f32_16x16x32_bf16(a_[m], b_[n], acc[m][n], 0, 0, 0);
            if (p + 1 < KTN) b_[n] = *(const bfrag*)(bpn + n * 512);
        }
        bp = bpn;
    }
}

// ---------------- HA/HB producer with fused LayerNorm -----------------------
// 32 nodes x 512 per block, grid.y=A/B. Wave w stages rows w*4..w*4+3:
// reads nf fp32 (8 floats/lane), butterfly-reduces mean/var over the wave,
// applies gamma/beta, packs bf16 to slab; y==0 also writes h for node_mlp.
__global__ __launch_bounds__(512, 4) void hab_gemm(
    const float* __restrict__ nf, const float* __restrict__ ln_g,
    const float* __restrict__ ln_b,
    const ushort* __restrict__ w1a_s, const ushort* __restrict__ w1b_s,
    ushort* __restrict__ h, ushort* __restrict__ HAp,
    ushort* __restrict__ HBp) {

    __shared__ __align__(16) ushort slab[32 * SLABW];   // 33 KB
    const int t = threadIdx.x;
    const int w = t >> 6;
    const int l = t & 63;
    const int q = l >> 4;
    const int ml = l & 15;
    const int rowbase = blockIdx.x * 32;
    const ushort* Bswz = blockIdx.y ? w1b_s : w1a_s;
    ushort* out = blockIdx.y ? HBp : HAp;

    // gamma/beta for this lane's 8 cols (row-invariant)
    float4 gv0 = *(const float4*)(ln_g + l * 8);
    float4 gv1 = *(const float4*)(ln_g + l * 8 + 4);
    float4 bv0 = *(const float4*)(ln_b + l * 8);
    float4 bv1 = *(const float4*)(ln_b + l * 8 + 4);

    for (int j = 0; j < 4; ++j) {
        int rr = w * 4 + j;
        int row = rowbase + rr;
        if (row >= N_NODES) row = N_NODES - 1;
        const float* xr = nf + (size_t)row * HD + l * 8;
        float4 v0 = *(const float4*)xr;
        float4 v1 = *(const float4*)(xr + 4);
        float s = v0.x + v0.y + v0.z + v0.w + v1.x + v1.y + v1.z + v1.w;
        float qq = v0.x * v0.x + v0.y * v0.y + v0.z * v0.z + v0.w * v0.w
                 + v1.x * v1.x + v1.y * v1.y + v1.z * v1.z + v1.w * v1.w;
        for (int o = 32; o; o >>= 1) {
            s  += __shfl_xor(s, o);
            qq += __shfl_xor(qq, o);
        }
        float m  = s * (1.0f / HD);
        float rs = rsqrtf(qq * (1.0f / HD) - m * m + 1e-5f);
        union { __hip_bfloat162 h2[4]; uint4 u4; } pk;
        pk.h2[0] = __float22bfloat162_rn(float2{(v0.x - m) * rs * gv0.x + bv0.x,
                                                (v0.y - m) * rs * gv0.y + bv0.y});
        pk.h2[1] = __float22bfloat162_rn(float2{(v0.z - m) * rs * gv0.z + bv0.z,
                                                (v0.w - m) * rs * gv0.w + bv0.w});
        pk.h2[2] = __float22bfloat162_rn(float2{(v1.x - m) * rs * gv1.x + bv1.x,
                                                (v1.y - m) * rs * gv1.y + bv1.y});
        pk.h2[3] = __float22bfloat162_rn(float2{(v1.z - m) * rs * gv1.z + bv1.z,
                                                (v1.w - m) * rs * gv1.w + bv1.w});
        *(uint4*)&slab[rr * SLABW + l * 8] = pk.u4;
        if (blockIdx.y == 0)
            *(uint4*)(h + (size_t)row * HD + l * 8) = pk.u4;
    }
    __syncthreads();

    ffrag acc[2][4];
    for (int m = 0; m < 2; ++m)
        for (int n = 0; n < 4; ++n)
            acc[m][n] = (ffrag){0.f, 0.f, 0.f, 0.f};

    kloop_rot<16, 2>(acc, slab, Bswz + ((size_t)(w << 2) * 64 + l) * 8, ml, q);

    for (int m = 0; m < 2; ++m)
        for (int rr = 0; rr < 4; ++rr) {
            int grow = rowbase + 16 * m + 4 * q + rr;
            if (grow < N_NODES) {
                union { __hip_bfloat162 h2[2]; ushort4 u4; } pk;
                pk.h2[0] = __float22bfloat162_rn(float2{acc[m][0][rr], acc[m][1][rr]});
                pk.h2[1] = __float22bfloat162_rn(float2{acc[m][2][rr], acc[m][3][rr]});
                *(ushort4*)(out + (size_t)grow * HD + w * 64 + ml * 4) = pk.u4;
            }
        }
}

// ---------------- Fused edge MLP (64 edges x 512 cols per block) ------------
// Exact R15/R19 structure (verified optimum: 318us).
__global__ __launch_bounds__(512, 4) void edge_mlp(
    const ushort* __restrict__ HAp,   const ushort* __restrict__ HBp,
    const float* __restrict__ LATBp,  const ushort* __restrict__ w1c,
    const ushort* __restrict__ w2s,   const float* __restrict__ b2,
    float* __restrict__ agg,
    const int* __restrict__ edge_index, const int* __restrict__ e2g,
    const float* __restrict__ frac_diff, const int* __restrict__ ebuf) {

    __shared__ __align__(16) ushort slab[64 * SLABW];     // 66560 B
    __shared__ int   ssrc[64];
    __shared__ int   sdst[64];
    __shared__ int   sgrp[64];
    __shared__ float sfd[64 * 3];

    const int t = threadIdx.x;        // 512 threads = 8 waves
    const int w = t >> 6;
    const int l = t & 63;
    const int q = l >> 4;
    const int ml = l & 15;
    const int rowbase = blockIdx.x * 64;

    if (t < 64) {
        int eid = ebuf[rowbase + t];
        ssrc[t] = edge_index[eid];
        sdst[t] = edge_index[N_EDGES + eid];
        sgrp[t] = e2g[eid];
        for (int c = 0; c < 3; ++c) sfd[t * 3 + c] = frac_diff[(size_t)eid * 3 + c];
    }
    __syncthreads();

    // ---- acc init: direct permuted loads (L2/L3-hot) ----
    ffrag acc[4][4];
    {
        const int cb = w * 64 + ml * 4;
        for (int m = 0; m < 4; ++m)
            for (int rr = 0; rr < 4; ++rr) {
                int rowl = 16 * m + 4 * q + rr;
                ushort4 a4 = *(const ushort4*)(HAp + (size_t)ssrc[rowl] * HD + cb);
                ushort4 h4 = *(const ushort4*)(HBp + (size_t)sdst[rowl] * HD + cb);
                float4  l4 = *(const float4*)(LATBp + (size_t)sgrp[rowl] * HD + cb);
                acc[m][0][rr] = bf2f(a4.x) + bf2f(h4.x) + l4.x;
                acc[m][1][rr] = bf2f(a4.y) + bf2f(h4.y) + l4.y;
                acc[m][2][rr] = bf2f(a4.z) + bf2f(h4.z) + l4.z;
                acc[m][3][rr] = bf2f(a4.w) + bf2f(h4.w) + l4.w;
            }
    }

    const int r  = t >> 3;            // staging row 0..63
    const int c0 = (t & 7) * 4;       // staging col 0..28 step 4
    float fd3[3] = { sfd[r * 3 + 0], sfd[r * 3 + 1], sfd[r * 3 + 2] };

    // ---- sin/cos staging via angle-addition recurrence (R12-verified) ----
    auto stage = [&](int phase) {
        float s = 0.f, c = 0.f, sx = 0.f, cx = 0.f, s16 = 0.f, c16 = 0.f;
        int dcur = -1;
        #pragma unroll
        for (int i = 0; i < 12; ++i) {
            int cc = c0 + 32 * i;                // 0..380 slab col
            int cp = phase * 384 + cc;           // global C-col
            int d = cp >> 8;
            if (d != dcur) {
                dcur = d;
                float x = fd3[d];
                float rx = __builtin_amdgcn_fractf(x);
                sx  = __builtin_amdgcn_sinf(rx);
                cx  = __builtin_amdgcn_cosf(rx);
                float r16 = __builtin_amdgcn_fractf(16.0f * x);
                s16 = __builtin_amdgcn_sinf(r16);
                c16 = __builtin_amdgcn_cosf(r16);
                int k0 = (cp & 255) >> 1;
                float r0 = __builtin_amdgcn_fractf((float)k0 * x);
                s = __builtin_amdgcn_sinf(r0);
                c = __builtin_amdgcn_cosf(r0);
            } else {
                float ns = s * c16 + c * s16;    // advance by 16x
                float nc = c * c16 - s * s16;
                s = ns; c = nc;
            }
            float s1 = s * cx + c * sx;          // partner k+1 (step x)
            float c1 = c * cx - s * sx;
            union { __hip_bfloat162 h2[2]; ushort4 u4; } pk;
            pk.h2[0] = __float22bfloat162_rn(float2{s, c});
            pk.h2[1] = __float22bfloat162_rn(float2{s1, c1});
            *(ushort4*)&slab[r * SLABW + cc] = pk.u4;
        }
    };

    const ushort* bpw1 = w1c + ((size_t)(w << 2) * 64 + l) * 8;
    const ushort* bpw2 = w2s + ((size_t)(w << 2) * 64 + l) * 8;

    stage(0);
    __syncthreads();
    kloop_rot<12, 4>(acc, slab, bpw1, ml, q);
    __syncthreads();
    stage(1);
    __syncthreads();
    kloop_rot<12, 4>(acc, slab, bpw1 + (size_t)12 * KSTR, ml, q);
    __syncthreads();

    // ---- e1 = silu(acc) -> slab in cperm layout (cvt_pk + b64); reset acc --
    for (int m = 0; m < 4; ++m)
        for (int rr = 0; rr < 4; ++rr) {
            int rowl = 16 * m + 4 * q + rr;
            union { __hip_bfloat162 h2[2]; ushort4 u4; } pk;
            pk.h2[0] = __float22bfloat162_rn(
                float2{silu_f(acc[m][0][rr]), silu_f(acc[m][1][rr])});
            pk.h2[1] = __float22bfloat162_rn(
                float2{silu_f(acc[m][2][rr]), silu_f(acc[m][3][rr])});
            *(ushort4*)&slab[rowl * SLABW + w * 64 + ml * 4] = pk.u4;
        }
    for (int m = 0; m < 4; ++m)
        for (int n = 0; n < 4; ++n)
            acc[m][n] = (ffrag){0.f, 0.f, 0.f, 0.f};
    __syncthreads();

    // ---- GEMM2 straight from the perm slab (w2s has invperm K-rows) ----
    kloop_rot<16, 4>(acc, slab, bpw2, ml, q);

    // ---- silu + b2 -> cperm fp32 fs (float4) + split segment reduce ----
    float* fs = (float*)slab;            // 64 x FSW fp32 (66560 B exact)
    float bv0 = b2[w * 64 + 0 * 16 + ml];
    float bv1 = b2[w * 64 + 1 * 16 + ml];
    float bv2 = b2[w * 64 + 2 * 16 + ml];
    float bv3 = b2[w * 64 + 3 * 16 + ml];
    for (int hh = 0; hh < 2; ++hh) {
        __syncthreads();
        if ((w >> 2) == hh) {
            int lcb = w * 64 + ml * 4 - hh * 256;   // local cperm col base
            for (int m = 0; m < 4; ++m)
                for (int rr = 0; rr < 4; ++rr) {
                    int rowl = 16 * m + 4 * q + rr;
                    float4 v = float4{silu_f(acc[m][0][rr] + bv0),
                                      silu_f(acc[m][1][rr] + bv1),
                                      silu_f(acc[m][2][rr] + bv2),
                                      silu_f(acc[m][3][rr] + bv3)};
                    *(float4*)&fs[rowl * FSW + lcb] = v;
                }
        }
        __syncthreads();
        {
            int col = t & 255;
            int r0 = (t >> 8) * 32;
            int cur = ssrc[r0];
            float run = 0.f;
            for (int j = 0; j < 32; ++j) {
                int rr2 = r0 + j;
                int nd = ssrc[rr2];
                if (nd != cur) {
                    unsafeAtomicAdd(&agg[(size_t)cur * HD + hh * 256 + col], run);
                    run = 0.f; cur = nd;
                }
                run += fs[rr2 * FSW + col];
            }
            unsafeAtomicAdd(&agg[(size_t)cur * HD + hh * 256 + col], run);
        }
    }
}

// ---------------- Fused node MLP (32 nodes x 512 cols per block) ------------
// aggdiv inlined: second staging reads agg fp32 + rp, divides by deg
// (wave-uniform per row), converts to bf16 in-register.
__global__ __launch_bounds__(512, 4) void node_mlp(
    const ushort* __restrict__ h,     const float* __restrict__ agg,
    const int* __restrict__ rp,
    const ushort* __restrict__ wn1s,  const ushort* __restrict__ wn2s,
    const float* __restrict__ b1,     const float* __restrict__ b2,
    const float* __restrict__ nf,     float* __restrict__ out) {

    __shared__ __align__(16) ushort slab[32 * SLABW];   // 33 KB

    const int t = threadIdx.x;        // 512 threads = 8 waves
    const int w = t >> 6;
    const int l = t & 63;
    const int q = l >> 4;
    const int ml = l & 15;
    const int rowbase = blockIdx.x * 32;

    ffrag acc[2][4];
    for (int m = 0; m < 2; ++m)
        for (int n = 0; n < 4; ++n)
            acc[m][n] = (ffrag){0.f, 0.f, 0.f, 0.f};

    const ushort* bp1 = wn1s + ((size_t)(w << 2) * 64 + l) * 8;
    const ushort* bp2 = wn2s + ((size_t)(w << 2) * 64 + l) * 8;

    // stage h rows
    for (int j = 0; j < 4; ++j) {
        int rr = w * 4 + j;
        int row = rowbase + rr;
        if (row >= N_NODES) row = N_NODES - 1;
        *(uint4*)&slab[rr * SLABW + l * 8] =
            *(const uint4*)(h + (size_t)row * HD + l * 8);
    }
    __syncthreads();
    kloop_rot<16, 2>(acc, slab, bp1, ml, q);
    __syncthreads();

    // stage agg rows / deg -> bf16 (inlined aggdiv)
    for (int j = 0; j < 4; ++j) {
        int rr = w * 4 + j;
        int row = rowbase + rr;
        if (row >= N_NODES) row = N_NODES - 1;
        int deg = rp[row + 1] - rp[row];
        float rc = __builtin_amdgcn_rcpf((float)max(deg, 1));
        const float4* ap = (const float4*)(agg + (size_t)row * HD + l * 8);
        float4 v0 = ap[0], v1 = ap[1];
        union { __hip_bfloat162 h2[4]; uint4 u4; } pk;
        pk.h2[0] = __float22bfloat162_rn(float2{v0.x * rc, v0.y * rc});
        pk.h2[1] = __float22bfloat162_rn(float2{v0.z * rc, v0.w * rc});
        pk.h2[2] = __float22bfloat162_rn(float2{v1.x * rc, v1.y * rc});
        pk.h2[3] = __float22bfloat162_rn(float2{v1.z * rc, v1.w * rc});
        *(uint4*)&slab[rr * SLABW + l * 8] = pk.u4;
    }
    __syncthreads();
    kloop_rot<16, 2>(acc, slab, bp1 + (size_t)16 * KSTR, ml, q);
    __syncthreads();

    {
        float bv[4];
        for (int n = 0; n < 4; ++n) bv[n] = b1[w * 64 + n * 16 + ml];
        for (int m = 0; m < 2; ++m)
            for (int rr = 0; rr < 4; ++rr) {
                int rowl = 16 * m + 4 * q + rr;
                union { __hip_bfloat162 h2[2]; ushort4 u4; } pk;
                pk.h2[0] = __float22bfloat162_rn(
                    float2{silu_f(acc[m][0][rr] + bv[0]), silu_f(acc[m][1][rr] + bv[1])});
                pk.h2[1] = __float22bfloat162_rn(
                    float2{silu_f(acc[m][2][rr] + bv[2]), silu_f(acc[m][3][rr] + bv[3])});
                *(ushort4*)&slab[rowl * SLABW + w * 64 + ml * 4] = pk.u4;
            }
    }
    for (int m = 0; m < 2; ++m)
        for (int n = 0; n < 4; ++n)
            acc[m][n] = (ffrag){0.f, 0.f, 0.f, 0.f};
    __syncthreads();

    kloop_rot<16, 2>(acc, slab, bp2, ml, q);

    for (int n = 0; n < 4; ++n) {
        int cg = w * 64 + n * 16 + ml;
        float bv = b2[cg];
        for (int m = 0; m < 2; ++m)
            for (int rr = 0; rr < 4; ++rr) {
                int rowl = 16 * m + 4 * q + rr;
                int row = rowbase + rowl;
                if (row < N_NODES) {
                    float v = silu_f(acc[m][n][rr] + bv);
                    out[(size_t)row * HD + cg] = nf[(size_t)row * HD + cg] + v;
                }
            }
    }
}

// ---------------------------------------------------------------------------
extern "C" void kernel_launch(void* const* d_in, const int* in_sizes, int n_in,
                              void* d_out, int out_size, void* d_ws, size_t ws_size,
                              hipStream_t stream) {
    const float* nf      = (const float*)d_in[0];
    const float* latt    = (const float*)d_in[1];
    const int*   eidx    = (const int*)d_in[2];
    const int*   e2g     = (const int*)d_in[3];
    const float* fd      = (const float*)d_in[4];
    const float* ln_g    = (const float*)d_in[6];
    const float* ln_b    = (const float*)d_in[7];
    const float* W_e1    = (const float*)d_in[8];
    const float* b_e1    = (const float*)d_in[9];
    const float* W_e2    = (const float*)d_in[10];
    const float* b_e2    = (const float*)d_in[11];
    const float* W_n1    = (const float*)d_in[12];
    const float* b_n1    = (const float*)d_in[13];
    const float* W_n2    = (const float*)d_in[14];
    const float* b_n2    = (const float*)d_in[15];
    float* out = (float*)d_out;

    auto al = [](size_t x) { return (x + 511) & ~(size_t)511; };
    size_t off_h    = 0;                         size_t sz_h    = (size_t)N_NODES * HD * 2;
    size_t off_w1a  = al(off_h + sz_h);          size_t sz_w1a  = (size_t)HD * HD * 2;
    size_t off_w1b  = al(off_w1a + sz_w1a);      size_t sz_w1b  = (size_t)HD * HD * 2;
    size_t off_w1c  = al(off_w1b + sz_w1b);      size_t sz_w1c  = (size_t)768 * HD * 2;
    size_t off_w2   = al(off_w1c + sz_w1c);      size_t sz_w2   = (size_t)HD * HD * 2;
    size_t off_wn1  = al(off_w2 + sz_w2);        size_t sz_wn1  = (size_t)2 * HD * HD * 2;
    size_t off_wn2  = al(off_wn1 + sz_wn1);      size_t sz_wn2  = (size_t)HD * HD * 2;
    size_t off_ha   = al(off_wn2 + sz_wn2);      size_t sz_ha   = (size_t)N_NODES * HD * 2;
    size_t off_hb   = al(off_ha + sz_ha);        size_t sz_hb   = (size_t)N_NODES * HD * 2;
    size_t off_lb   = al(off_hb + sz_hb);        size_t sz_lb   = (size_t)50 * HD * 4;
    size_t off_c32  = al(off_lb + sz_lb);        size_t sz_c32  = (size_t)N_NODES * 4;
    size_t off_cur  = al(off_c32 + sz_c32);      size_t sz_cur  = (size_t)N_NODES * 4;
    size_t off_rp   = al(off_cur + sz_cur);      size_t sz_rp   = (size_t)(N_NODES + 1) * 4;
    size_t off_ebuf = al(off_rp + sz_rp);        size_t sz_ebuf = (size_t)N_EDGES * 4;
    size_t off_agg  = al(off_ebuf + sz_ebuf);    size_t sz_agg  = (size_t)N_NODES * HD * 4;
    size_t need     = off_agg + sz_agg;

    if (ws_size < need) {
        sentinel_kernel<<<(out_size + 255) / 256, 256, 0, stream>>>(out, out_size);
        return;
    }

    char* ws = (char*)d_ws;
    ushort* h     = (ushort*)(ws + off_h);
    ushort* w1a_s = (ushort*)(ws + off_w1a);
    ushort* w1b_s = (ushort*)(ws + off_w1b);
    ushort* w1c_s = (ushort*)(ws + off_w1c);
    ushort* w2s   = (ushort*)(ws + off_w2);
    ushort* wn1s  = (ushort*)(ws + off_wn1);
    ushort* wn2s  = (ushort*)(ws + off_wn2);
    ushort* HAp   = (ushort*)(ws + off_ha);
    ushort* HBp   = (ushort*)(ws + off_hb);
    float*  LATBp = (float*)(ws + off_lb);
    int*    c32   = (int*)(ws + off_c32);
    int*    cur   = (int*)(ws + off_cur);
    int*    rp    = (int*)(ws + off_rp);
    int*    ebuf  = (int*)(ws + off_ebuf);
    float*  agg   = (float*)(ws + off_agg);

    // fused prep: zero + 6x wswz + latb (one launch, 6010 blocks)
    prep_kernel<<<6010, 256, 0, stream>>>(
        W_e1, W_e2, W_n1, W_n2, latt, b_e1,
        w1a_s, w1b_s, w1c_s, w2s, wn1s, wn2s, LATBp, c32, (float4*)agg);

    // CSR build (edges sorted by src node)
    hist_kernel<<<(N_EDGES + 255) / 256, 256, 0, stream>>>(eidx, c32);
    scan_kernel<<<1, 1024, 0, stream>>>(c32, rp, cur);
    csr_fill<<<(N_EDGES + 255) / 256, 256, 0, stream>>>(eidx, cur, ebuf);

    // LN fused into HA/HB producer (writes h for node_mlp from y==0)
    hab_gemm<<<dim3(313, 2), 512, 0, stream>>>(
        nf, ln_g, ln_b, w1a_s, w1b_s, h, HAp, HBp);

    // fused edge MLP (CSR order) -> agg (cperm col space)
    edge_mlp<<<N_EDGES / 64, 512, 0, stream>>>(
        HAp, HBp, LATBp, w1c_s, w2s, b_e2, agg, eidx, e2g, fd, ebuf);

    // fused node MLP (aggdiv inlined; 313 blocks)
    int nblocks = (N_NODES + 31) / 32;
    node_mlp<<<nblocks, 512, 0, stream>>>(h, agg, rp, wn1s, wn2s, b_n1, b_n2, nf, out);
}